// Round 8
// baseline (273.421 us; speedup 1.0000x reference)
//
#include <hip/hip_runtime.h>
#include <hip/hip_bf16.h>
#include <stdint.h>

// ---------------------------------------------------------------------------
// E=64 H=64 PRE1=512 BNK=1024 S=256 P=16 B=4096. Attention branch dead
// (softmax over size-1 axis == 1). Decomposition (rel is rank-2):
//   Z1[s,i,j,k] = rx*MX[k] + ry*MY[k] + HH[16s+j][k];  Y1 = relu(Z1)
//   out = maxpool_j relu(bn2(Y1 @ Wp2))
// v7: barrier-free K-loop. WG = (scene, N-eighth), 512 thr = 8 waves.
//     The WG's whole B slab (8 nt x 16 ks = 128 KB) is DMA'd to LDS ONCE;
//     the 16-ks loop has NO barriers -> waves desync and keep the matrix
//     pipe fed (v4/v5/v6 all plateaued at MfmaUtil ~24% = pure pipe work,
//     phase-locked by per-ks barriers / load latency).
//     HH (16x512) computed inside mm2 via 8 MFMAs/wave from L2-hot packed
//     W1b (hh_kernel dispatch + 8 MB HH round-trip eliminated).
//     2 dispatches total. LDS 148.7 KB -> 1 WG/CU, 8 free-running waves.
// ---------------------------------------------------------------------------

typedef __bf16 bf16x8 __attribute__((ext_vector_type(8)));
typedef __bf16 bf16x2 __attribute__((ext_vector_type(2)));
typedef float  f32x4  __attribute__((ext_vector_type(4)));
typedef float  f32x2  __attribute__((ext_vector_type(2)));

// workspace layout (bytes)
#define BP2_OFF 0u          // packed Wp2: [nt(64)][ks(16)][l(64)]*16B = 1 MB
#define BP1_OFF 1048576u    // packed W1b (Wp1 rows 64..127): [nt(32)][kb(2)][l]*16B = 64 KB
#define MX_OFF  1114112u    // 512 f32
#define MY_OFF  1116160u
#define CB_OFF  1118208u
#define SH_OFF  1120256u
#define A2_OFF  1122304u    // 1024 f32
#define C2_OFF  1126400u
// total ~1.08 MB

// mm2 LDS layout (bytes)
#define BB_LDS  0           // 128 KB: this WG's Wp2 eighth, frag order [ntl(8)][ks(16)][l(64)][16B]
#define HH_LDS  131072      // bf16 [16 j][512 k], row stride 1040 B (bank-rotated) = 16640 B
#define MX_LDS  147712      // f32[512]
#define MY_LDS  149760      // f32[512]
#define LDS_SZ  151808      // 148.2 KB

__device__ __forceinline__ unsigned short f2bf(float f) {
    union { float f; unsigned u; } c; c.f = f;
    unsigned u = c.u;
    return (unsigned short)((u + 0x7fffu + ((u >> 16) & 1u)) >> 16);
}
__device__ __forceinline__ float bfbits2f(unsigned hi) {
    union { unsigned u; float f; } c; c.u = hi; return c.f;
}
__device__ __forceinline__ unsigned pk_bf16(float a, float b) {
#if __has_builtin(__builtin_amdgcn_cvt_pk_bf16_f32)
    bf16x2 p = __builtin_amdgcn_cvt_pk_bf16_f32(a, b);
    union { bf16x2 v; unsigned u; } c; c.v = p; return c.u;
#else
    return (unsigned)f2bf(a) | ((unsigned)f2bf(b) << 16);
#endif
}

typedef const __attribute__((address_space(1))) unsigned int* gas_t;
typedef __attribute__((address_space(3))) unsigned int* las_t;
__device__ __forceinline__ void dma16(const void* g, void* l) {
    __builtin_amdgcn_global_load_lds((gas_t)g, (las_t)l, 16, 0, 0);
}

// ---------------------------------------------------------------------------
// prep_pack: blocks 0..255 pack Wp2, 256..271 pack W1b (LDS transpose,
// coalesced float4 reads), 272..273 fold k-consts, 274..277 fold A2/C2.
// B-frag (16x16x32): lane l holds B[k=kb*32+(l>>4)*8+j][n=nt*16+(l&15)],
// packed at ((nt*KB+kb)*64+l)*16 bytes.
// ---------------------------------------------------------------------------
__global__ __launch_bounds__(256) void prep_pack_kernel(
    const float* __restrict__ Wsp,  const float* __restrict__ bsp,
    const float* __restrict__ Wp1,  const float* __restrict__ bp1,
    const float* __restrict__ gp1,  const float* __restrict__ btp1,
    const float* __restrict__ mp1,  const float* __restrict__ vp1,
    const float* __restrict__ Wp2,  const float* __restrict__ bp2,
    const float* __restrict__ gp2,  const float* __restrict__ btp2,
    const float* __restrict__ mp2,  const float* __restrict__ vp2,
    unsigned char* __restrict__ ws)
{
    __shared__ float tile[32 * 65];
    const int blk = blockIdx.x, t = threadIdx.x;

    if (blk < 272) {
        const float* src; int ncols, kb, ng, KB; unsigned outoff;
        if (blk < 256) { kb = blk >> 4; ng = blk & 15; src = Wp2; ncols = 1024; KB = 16; outoff = BP2_OFF; }
        else { int b2 = blk - 256; kb = b2 >> 3; ng = b2 & 7; src = Wp1 + 64 * 512; ncols = 512; KB = 2; outoff = BP1_OFF; }
        const int k0 = kb * 32, n0 = ng * 64;
        #pragma unroll
        for (int it = 0; it < 2; ++it) {
            int c = t + it * 256;
            int r = c >> 4, c4 = c & 15;
            float4 v = *(const float4*)(src + (k0 + r) * ncols + n0 + c4 * 4);
            tile[r * 65 + c4 * 4 + 0] = v.x;
            tile[r * 65 + c4 * 4 + 1] = v.y;
            tile[r * 65 + c4 * 4 + 2] = v.z;
            tile[r * 65 + c4 * 4 + 3] = v.w;
        }
        __syncthreads();
        int ntl = t >> 6, l = t & 63;
        int nl = ntl * 16 + (l & 15), kl = (l >> 4) * 8;
        uint4 o;
        o.x = pk_bf16(tile[(kl + 0) * 65 + nl], tile[(kl + 1) * 65 + nl]);
        o.y = pk_bf16(tile[(kl + 2) * 65 + nl], tile[(kl + 3) * 65 + nl]);
        o.z = pk_bf16(tile[(kl + 4) * 65 + nl], tile[(kl + 5) * 65 + nl]);
        o.w = pk_bf16(tile[(kl + 6) * 65 + nl], tile[(kl + 7) * 65 + nl]);
        ((uint4*)(ws + outoff))[((ng * 4 + ntl) * KB + kb) * 64 + l] = o;
    } else if (blk < 274) {
        int k = (blk - 272) * 256 + t;
        float a1 = gp1[k] * rsqrtf(vp1[k] + 1e-5f);
        float mx = 0.f, my = 0.f, cb = 0.f;
        for (int e = 0; e < 64; ++e) {
            float wv = Wp1[e * 512 + k];
            mx = fmaf(Wsp[e],      wv, mx);
            my = fmaf(Wsp[64 + e], wv, my);
            cb = fmaf(bsp[e],      wv, cb);
        }
        ((float*)(ws + MX_OFF))[k] = 0.05f * a1 * mx;
        ((float*)(ws + MY_OFF))[k] = 0.05f * a1 * my;
        ((float*)(ws + CB_OFF))[k] = 0.05f * a1 * cb + (bp1[k] - mp1[k]) * a1 + btp1[k];
        ((float*)(ws + SH_OFF))[k] = 0.05f * a1;
    } else {
        int n = (blk - 274) * 256 + t;
        float a = gp2[n] * rsqrtf(vp2[n] + 1e-5f);
        ((float*)(ws + A2_OFF))[n] = a;
        ((float*)(ws + C2_OFF))[n] = btp2[n] + (bp2[n] - mp2[n]) * a;
    }
}

// ---------------------------------------------------------------------------
// mm2 v7: WG = (scene s, N-eighth ne). 512 thr = 8 waves.
// Setup (one barrier): DMA Wp2 slab -> BB_LDS; stage MX/MY; compute HH
// (16 j x 512 k) via 8 MFMAs/wave from h (global) x packed W1b (global,
// L2-hot); ds_write HH bf16; rx/ry straight from global epos.
// K-loop (ks=0..15, NO barriers): wave w = (ig=w>>1: 4 i-rowtiles,
// ng=w&1: 4 ntiles). A-frags built on the fly (packed f32 fma/max),
// B-frags ds_read_b128 from BB_LDS. acc[4][4] = 64 regs.
// Epilogue: bn2+relu, maxpool over j (4-reg max + 2 shfl_xor), fp32 store.
// ---------------------------------------------------------------------------
__global__ __launch_bounds__(512, 2) void mm2_kernel(
    const float* __restrict__ hst,
    const float* __restrict__ epos,
    const unsigned char* __restrict__ ws,
    float* __restrict__ out)
{
    __shared__ __align__(16) unsigned char smem[LDS_SZ];

    const int s   = blockIdx.x >> 3;     // 256 scenes
    const int ne  = blockIdx.x & 7;      // 8 N-eighths
    const int tid = threadIdx.x;
    const int w    = tid >> 6;           // 0..7
    const int l    = tid & 63;
    const int quad = l >> 4;
    const int jl   = l & 15;
    const int ig   = w >> 1;             // i-group 0..3
    const int ng   = w & 1;              // n-group 0..1

    // ---- issue DMA of this WG's Wp2 slab (128 KB) immediately ----
    {
        const unsigned char* src = ws + BP2_OFF + (unsigned)ne * 131072u;
        #pragma unroll
        for (int r = 0; r < 16; ++r) {
            int idx = (tid + r * 512) << 4;
            dma16(src + idx, smem + BB_LDS + idx);
        }
    }

    // ---- stage MX/MY ----
    ((float*)(smem + MX_LDS))[tid] = ((const float*)(ws + MX_OFF))[tid];
    ((float*)(smem + MY_LDS))[tid] = ((const float*)(ws + MY_OFF))[tid];

    // ---- HH compute: HH[j][k] = SH[k]*(h[s16+j] @ W1b)[k] + CB[k] ----
    {
        // A-frags from h (row j = jl, cols kb*32 + quad*8 .. +8)
        union { unsigned u[4]; bf16x8 v; } afh[2];
        #pragma unroll
        for (int kb = 0; kb < 2; ++kb) {
            const float4* hp = (const float4*)(hst + (s * 16 + jl) * 64 + kb * 32 + quad * 8);
            float4 v0 = hp[0], v1 = hp[1];
            afh[kb].u[0] = pk_bf16(v0.x, v0.y);
            afh[kb].u[1] = pk_bf16(v0.z, v0.w);
            afh[kb].u[2] = pk_bf16(v1.x, v1.y);
            afh[kb].u[3] = pk_bf16(v1.z, v1.w);
        }
        const f32x4 fz = {0.f, 0.f, 0.f, 0.f};
        f32x4 acch[4] = {fz, fz, fz, fz};    // wave w covers ntiles w*4..+3 of 32
        #pragma unroll
        for (int kb = 0; kb < 2; ++kb) {
            #pragma unroll
            for (int ct = 0; ct < 4; ++ct) {
                bf16x8 bfr = *(const bf16x8*)(ws + BP1_OFF + ((((w * 4 + ct) * 2 + kb) * 64 + l) << 4));
                acch[ct] = __builtin_amdgcn_mfma_f32_16x16x32_bf16(afh[kb].v, bfr, acch[ct], 0, 0, 0);
            }
        }
        const float* SHg = (const float*)(ws + SH_OFF);
        const float* CBg = (const float*)(ws + CB_OFF);
        #pragma unroll
        for (int ct = 0; ct < 4; ++ct) {
            int col = (w * 4 + ct) * 16 + jl;         // k index
            float sh = SHg[col], cb = CBg[col];
            #pragma unroll
            for (int reg = 0; reg < 4; ++reg) {
                int row = quad * 4 + reg;             // j index
                float hv = fmaf(acch[ct][reg], sh, cb);
                *(unsigned short*)(smem + HH_LDS + row * 1040 + col * 2) = f2bf(hv);
            }
        }
    }

    // ---- rx/ry straight from global epos (no LDS staging) ----
    float rxv[4], ryv[4];
    {
        float pjx = epos[s * 32 + jl * 2], pjy = epos[s * 32 + jl * 2 + 1];
        #pragma unroll
        for (int rb = 0; rb < 4; ++rb) {
            int i = ig * 4 + rb;
            rxv[rb] = pjx - epos[s * 32 + i * 2];
            ryv[rb] = pjy - epos[s * 32 + i * 2 + 1];
        }
    }

    __syncthreads();   // drains B DMA (vmcnt) + HH/MX/MY LDS writes. ONLY barrier.

    const f32x4 fzero = {0.f, 0.f, 0.f, 0.f};
    f32x4 acc[4][4];
    #pragma unroll
    for (int rb = 0; rb < 4; ++rb)
        #pragma unroll
        for (int ct = 0; ct < 4; ++ct) acc[rb][ct] = fzero;

    const f32x2 zero2 = {0.f, 0.f};

    // ---- barrier-free K-loop ----
    #pragma unroll 2
    for (int ks = 0; ks < 16; ++ks) {
        // MX/MY (quad-broadcast reads) for k = ks*32 + quad*8 .. +8
        int mo = (ks * 32 + quad * 8) * 4;
        f32x4 mx0 = *(const f32x4*)(smem + MX_LDS + mo);
        f32x4 mx1 = *(const f32x4*)(smem + MX_LDS + mo + 16);
        f32x4 my0 = *(const f32x4*)(smem + MY_LDS + mo);
        f32x4 my1 = *(const f32x4*)(smem + MY_LDS + mo + 16);
        // HH frag (shared by all 4 rowtiles): bf16x8 at row jl
        uint4 hhb = *(const uint4*)(smem + HH_LDS + jl * 1040 + ks * 64 + quad * 16);

        f32x2 mxp[4] = { __builtin_shufflevector(mx0, mx0, 0, 1),
                         __builtin_shufflevector(mx0, mx0, 2, 3),
                         __builtin_shufflevector(mx1, mx1, 0, 1),
                         __builtin_shufflevector(mx1, mx1, 2, 3) };
        f32x2 myp[4] = { __builtin_shufflevector(my0, my0, 0, 1),
                         __builtin_shufflevector(my0, my0, 2, 3),
                         __builtin_shufflevector(my1, my1, 0, 1),
                         __builtin_shufflevector(my1, my1, 2, 3) };
        f32x2 hhp[4];
        {
            unsigned d0 = hhb.x, d1 = hhb.y, d2 = hhb.z, d3 = hhb.w;
            hhp[0][0] = bfbits2f(d0 << 16); hhp[0][1] = bfbits2f(d0 & 0xffff0000u);
            hhp[1][0] = bfbits2f(d1 << 16); hhp[1][1] = bfbits2f(d1 & 0xffff0000u);
            hhp[2][0] = bfbits2f(d2 << 16); hhp[2][1] = bfbits2f(d2 & 0xffff0000u);
            hhp[3][0] = bfbits2f(d3 << 16); hhp[3][1] = bfbits2f(d3 & 0xffff0000u);
        }

        // B frags for this wave's 4 ntiles
        bf16x8 bfr[4];
        #pragma unroll
        for (int ct = 0; ct < 4; ++ct)
            bfr[ct] = *(const bf16x8*)(smem + BB_LDS + (((ng * 4 + ct) * 16 + ks) << 10) + (l << 4));

        // Construct A-frags + MFMA
        #pragma unroll
        for (int rb = 0; rb < 4; ++rb) {
            f32x2 rx2 = { rxv[rb], rxv[rb] };
            f32x2 ry2 = { ryv[rb], ryv[rb] };
            union { unsigned u[4]; bf16x8 v; } af;
            #pragma unroll
            for (int p = 0; p < 4; ++p) {
                f32x2 tt = __builtin_elementwise_fma(ry2, myp[p], hhp[p]);
                tt = __builtin_elementwise_fma(rx2, mxp[p], tt);
                tt = __builtin_elementwise_max(tt, zero2);
                af.u[p] = pk_bf16(tt[0], tt[1]);
            }
            #pragma unroll
            for (int ct = 0; ct < 4; ++ct)
                acc[rb][ct] = __builtin_amdgcn_mfma_f32_16x16x32_bf16(af.v, bfr[ct], acc[rb][ct], 0, 0, 0);
        }
    }

    // ---- epilogue: bn2 + relu, maxpool over j (D rows), store fp32 ----
    const float* A2 = (const float*)(ws + A2_OFF);
    const float* C2 = (const float*)(ws + C2_OFF);
    #pragma unroll
    for (int ct = 0; ct < 4; ++ct) {
        int col = (ne * 8 + ng * 4 + ct) * 16 + jl;
        float a2 = A2[col], c2 = C2[col];
        #pragma unroll
        for (int rb = 0; rb < 4; ++rb) {
            float v0 = fmaxf(fmaf(acc[rb][ct][0], a2, c2), 0.f);
            float v1 = fmaxf(fmaf(acc[rb][ct][1], a2, c2), 0.f);
            float v2 = fmaxf(fmaf(acc[rb][ct][2], a2, c2), 0.f);
            float v3 = fmaxf(fmaf(acc[rb][ct][3], a2, c2), 0.f);
            float v = fmaxf(fmaxf(v0, v1), fmaxf(v2, v3));
            v = fmaxf(v, __shfl_xor(v, 16, 64));
            v = fmaxf(v, __shfl_xor(v, 32, 64));
            if (l < 16) {
                int orow = s * 16 + ig * 4 + rb;
                __builtin_nontemporal_store(v, &out[orow * 1024 + col]);
            }
        }
    }
}

extern "C" void kernel_launch(void* const* d_in, const int* in_sizes, int n_in,
                              void* d_out, int out_size, void* d_ws, size_t ws_size,
                              hipStream_t stream) {
    const float* hst  = (const float*)d_in[0];
    const float* epos = (const float*)d_in[1];
    const float* Wsp  = (const float*)d_in[4];
    const float* bsp  = (const float*)d_in[5];
    const float* Wp1  = (const float*)d_in[20];
    const float* bp1  = (const float*)d_in[21];
    const float* gp1  = (const float*)d_in[22];
    const float* btp1 = (const float*)d_in[23];
    const float* mp1  = (const float*)d_in[24];
    const float* vp1  = (const float*)d_in[25];
    const float* Wp2  = (const float*)d_in[26];
    const float* bp2  = (const float*)d_in[27];
    const float* gp2  = (const float*)d_in[28];
    const float* btp2 = (const float*)d_in[29];
    const float* mp2  = (const float*)d_in[30];
    const float* vp2  = (const float*)d_in[31];
    unsigned char* ws = (unsigned char*)d_ws;
    float* out = (float*)d_out;

    // 256 (Wp2 pack) + 16 (W1b pack) + 2 (k-consts) + 4 (A2/C2) = 278 blocks
    prep_pack_kernel<<<278, 256, 0, stream>>>(Wsp, bsp, Wp1, bp1, gp1, btp1, mp1, vp1,
                                              Wp2, bp2, gp2, btp2, mp2, vp2, ws);
    // 256 scenes x 8 N-eighths, 512 threads (8 waves)
    mm2_kernel<<<2048, 512, 0, stream>>>(hst, epos, ws, out);
}